// Round 12
// baseline (463.485 us; speedup 1.0000x reference)
//
#include <hip/hip_runtime.h>
#include <math.h>

#define NPTS   131072
#define INF    512
#define ROWF   513      // 512 features + 1 cid column
#define NCASE  64
#define HID    512
#define NB     256      // stream chunks
#define CHUNK  512      // points per chunk

typedef float v4f __attribute__((ext_vector_type(4)));

// ---------------------------------------------------------------------------
// K_stream: sequential-stream per-case accumulation. Block b owns rows
// [b*512, b*512+512). acc[64][512] in LDS (128 KB); thread t owns feature t.
// Accumulate via unsafeAtomicAdd -> hardware ds_add_f32 (fire-and-forget,
// no CAS loop, no RMW latency chain). Deterministic: each (case,feature)
// address has exactly ONE writer thread, and same-thread LDS atomics retire
// in program order -> fixed summation order every run.
// NT loads (proven in R10; plain loads were not the R11 regression).
// ---------------------------------------------------------------------------
__global__ __launch_bounds__(512)
void k_stream(const float* __restrict__ x, float* __restrict__ psum,
              float* __restrict__ pcnt, int* __restrict__ cids) {
  __shared__ float acc[NCASE * HID];   // 128 KB
  __shared__ int   cidl[CHUNK];        // 2 KB
  __shared__ int   cnth[NCASE];
  const int t = threadIdx.x;           // 0..511
  const int b = blockIdx.x;
  const int base = b * CHUNK;

  for (int i = t; i < NCASE * HID; i += 512) acc[i] = 0.f;
  if (t < NCASE) cnth[t] = 0;
  __syncthreads();

  // phase 0: one point per thread -> cid, global cid cache, LDS count
  {
    float cf = x[(size_t)(base + t) * ROWF + INF];
    int c = (int)(cf + 0.5f);
    cidl[t] = c;
    cids[base + t] = c;
    atomicAdd(&cnth[c], 1);            // int atomic: hardware ds_add, exact
  }
  __syncthreads();

  const int f = t;                     // feature owned by this thread
  const float* xp = x + (size_t)base * ROWF + f;

  float v[8];
  #pragma unroll
  for (int j = 0; j < 8; ++j)
    v[j] = __builtin_nontemporal_load(xp + (size_t)j * ROWF);

  for (int p = 0; p < CHUNK; p += 8) {
    float nv[8];
    if (p + 8 < CHUNK) {
      #pragma unroll
      for (int j = 0; j < 8; ++j)
        nv[j] = __builtin_nontemporal_load(xp + (size_t)(p + 8 + j) * ROWF);
    }
    int cj[8];
    #pragma unroll
    for (int j = 0; j < 8; ++j) cj[j] = cidl[p + j];
    #pragma unroll
    for (int j = 0; j < 8; ++j) unsafeAtomicAdd(&acc[cj[j] * HID + f], v[j]);
    #pragma unroll
    for (int j = 0; j < 8; ++j) v[j] = nv[j];
  }
  __syncthreads();

  float* od = psum + (size_t)b * NCASE * HID;
  for (int c = 0; c < NCASE; ++c)
    od[c * HID + f] = acc[c * HID + f];
  if (t < NCASE) pcnt[b * NCASE + t] = (float)cnth[t];
}

// ---------------------------------------------------------------------------
// K_h0: h0[c][f] = (sum_b psum[b][c][f]) / max(cnt[c],1).
// grid (64 cases, 4 feature-quarters) x 128 threads.
// ---------------------------------------------------------------------------
__global__ __launch_bounds__(128)
void k_h0(const float* __restrict__ psum, const float* __restrict__ pcnt,
          float* __restrict__ h0) {
  __shared__ float cs[128];
  const int c  = blockIdx.x;
  const int fq = blockIdx.y;
  const int t  = threadIdx.x;
  const int f  = fq * 128 + t;

  const float* p = psum + (size_t)c * HID + f;
  float s = 0.f;
  #pragma unroll 8
  for (int b = 0; b < NB; ++b) s += p[(size_t)b * NCASE * HID];

  cs[t] = pcnt[t * NCASE + c] + pcnt[(t + 128) * NCASE + c];
  __syncthreads();
  for (int w = 64; w > 0; w >>= 1) {
    if (t < w) cs[t] += cs[t + w];
    __syncthreads();
  }
  float cnt = fmaxf(cs[0], 1.f);
  h0[(size_t)c * HID + f] = s / cnt;
}

// ---------------------------------------------------------------------------
// K_scale2: scale[row] = g[row] / ||V[row]|| for both layers in one launch.
// ---------------------------------------------------------------------------
__global__ __launch_bounds__(256)
void k_scale2(const float* __restrict__ V0, const float* __restrict__ g0,
              const float* __restrict__ V1, const float* __restrict__ g1,
              float* __restrict__ scale0, float* __restrict__ scale1) {
  __shared__ float red[256];
  const int row = blockIdx.x;               // 0..1023
  const int t   = threadIdx.x;
  const bool first = row < 512;
  const int r = first ? row : row - 512;
  const float* vr = (first ? V0 : V1) + (size_t)r * HID;
  float s = 0.f;
  for (int k = t; k < HID; k += 256) { float v = vr[k]; s += v * v; }
  red[t] = s;
  __syncthreads();
  for (int w = 128; w > 0; w >>= 1) {
    if (t < w) red[t] += red[t + w];
    __syncthreads();
  }
  if (t == 0) {
    float g = first ? g0[r] : g1[r];
    (first ? scale0 : scale1)[r] = g / sqrtf(red[0]);
  }
}

// ---------------------------------------------------------------------------
// K_layer: hout[n][o] = act( scale[o]*dot(hin[n], W[o]) + bias[o] ).
// ---------------------------------------------------------------------------
template <bool SILU, bool SCALED>
__global__ __launch_bounds__(256)
void k_layer(const float* __restrict__ hin, const float* __restrict__ W,
             const float* __restrict__ scale, const float* __restrict__ bias,
             float* __restrict__ hout) {
  __shared__ float hrow[HID];
  const int n = blockIdx.y;
  const int t = threadIdx.x;
  const int o = blockIdx.x * 256 + t;
  for (int f = t; f < HID; f += 256) hrow[f] = hin[(size_t)n * HID + f];
  __syncthreads();
  const float* wr = W + (size_t)o * HID;
  float s0 = 0.f, s1 = 0.f, s2 = 0.f, s3 = 0.f;
  for (int k = 0; k < HID; k += 4) {
    float4 h4 = *(const float4*)&hrow[k];
    float4 w4 = *(const float4*)&wr[k];
    s0 += h4.x * w4.x; s1 += h4.y * w4.y;
    s2 += h4.z * w4.z; s3 += h4.w * w4.w;
  }
  float sdot = (s0 + s1) + (s2 + s3);
  float y = SCALED ? (sdot * scale[o] + bias[o]) : (sdot + bias[o]);
  if (SILU) y = y / (1.f + expf(-y));
  hout[(size_t)n * HID + o] = y;
}

// ---------------------------------------------------------------------------
// K_scatter: natural-order broadcast; plain stores (L2 write-back path).
// Each block owns 128 contiguous points (256 KB of sequential stores).
// ---------------------------------------------------------------------------
__global__ __launch_bounds__(256)
void k_scatter(const int* __restrict__ cids, const float* __restrict__ h3,
               float* __restrict__ out) {
  __shared__ int cl[128];
  const int t = threadIdx.x;
  const int q = t & 127;                    // float4 index in row
  const int half = t >> 7;
  const int base = blockIdx.x * 128;
  if (t < 128) cl[t] = cids[base + t];
  __syncthreads();
  #pragma unroll 8
  for (int p = half; p < 128; p += 2) {
    int c = cl[p];
    v4f hv = ((const v4f*)(h3 + (size_t)c * HID))[q];
    ((v4f*)(out + (size_t)(base + p) * HID))[q] = hv;
  }
}

// ---------------------------------------------------------------------------
extern "C" void kernel_launch(void* const* d_in, const int* in_sizes, int n_in,
                              void* d_out, int out_size, void* d_ws, size_t ws_size,
                              hipStream_t stream) {
  const float* x  = (const float*)d_in[0];
  const float* V0 = (const float*)d_in[1];
  const float* g0 = (const float*)d_in[2];
  const float* b0 = (const float*)d_in[3];
  const float* V1 = (const float*)d_in[4];
  const float* g1 = (const float*)d_in[5];
  const float* b1 = (const float*)d_in[6];
  const float* Wf = (const float*)d_in[7];
  const float* bf = (const float*)d_in[8];
  float* out = (float*)d_out;
  float* ws  = (float*)d_ws;

  size_t off = 0;
  float* psum   = ws + off; off += (size_t)NB * NCASE * HID;    // 32 MB
  float* pcnt   = ws + off; off += NB * NCASE;
  float* h0     = ws + off; off += NCASE * HID;
  float* h1     = ws + off; off += NCASE * HID;
  float* h2     = ws + off; off += NCASE * HID;
  float* h3     = ws + off; off += NCASE * HID;
  float* scale0 = ws + off; off += 512;
  float* scale1 = ws + off; off += 512;
  int*   cids   = (int*)(ws + off); off += NPTS;

  k_scale2<<<dim3(1024), dim3(256), 0, stream>>>(V0, g0, V1, g1, scale0, scale1);
  k_stream<<<dim3(NB), dim3(512), 0, stream>>>(x, psum, pcnt, cids);
  k_h0    <<<dim3(NCASE, 4), dim3(128), 0, stream>>>(psum, pcnt, h0);
  k_layer<true,  true ><<<dim3(2, NCASE), dim3(256), 0, stream>>>(h0, V0, scale0, b0, h1);
  k_layer<true,  true ><<<dim3(2, NCASE), dim3(256), 0, stream>>>(h1, V1, scale1, b1, h2);
  k_layer<false, false><<<dim3(2, NCASE), dim3(256), 0, stream>>>(h2, Wf, nullptr, bf, h3);
  k_scatter<<<dim3(NPTS / 128), dim3(256), 0, stream>>>(cids, h3, out);
}

// Round 13
// 210.197 us; speedup vs baseline: 2.2050x; 2.2050x over previous
//
#include <hip/hip_runtime.h>
#include <math.h>

#define NPTS   131072
#define INF    512
#define ROWF   513      // 512 features + 1 cid column
#define NCASE  64
#define HID    512
#define NB     256      // stream chunks
#define CHUNK  512      // points per chunk

typedef float v4f __attribute__((ext_vector_type(4)));

// ---------------------------------------------------------------------------
// K_stream (R10-exact, measured-best ~86us): sequential-stream per-case
// accumulation. Block b owns rows [b*512, b*512+512). acc[64][512] in LDS;
// thread t owns feature t for ALL cases -> exclusive plain RMW (serialized by
// compiler, but 4.7x faster than LDS atomics per R11/R12), deterministic.
// ---------------------------------------------------------------------------
__global__ __launch_bounds__(512)
void k_stream(const float* __restrict__ x, float* __restrict__ psum,
              float* __restrict__ pcnt, int* __restrict__ cids) {
  __shared__ float acc[NCASE * HID];   // 128 KB
  __shared__ int   cidl[CHUNK];        // 2 KB
  __shared__ int   cnth[NCASE];
  const int t = threadIdx.x;           // 0..511
  const int b = blockIdx.x;
  const int base = b * CHUNK;

  for (int i = t; i < NCASE * HID; i += 512) acc[i] = 0.f;
  if (t < NCASE) cnth[t] = 0;
  __syncthreads();

  // phase 0: one point per thread -> cid, global cid cache, LDS count
  {
    float cf = x[(size_t)(base + t) * ROWF + INF];
    int c = (int)(cf + 0.5f);
    cidl[t] = c;
    cids[base + t] = c;
    atomicAdd(&cnth[c], 1);
  }
  __syncthreads();

  const int f = t;                     // feature owned by this thread
  const float* xp = x + (size_t)base * ROWF + f;

  float v[8];
  #pragma unroll
  for (int j = 0; j < 8; ++j)
    v[j] = xp[(size_t)j * ROWF];

  for (int p = 0; p < CHUNK; p += 8) {
    float nv[8];
    if (p + 8 < CHUNK) {
      #pragma unroll
      for (int j = 0; j < 8; ++j)
        nv[j] = xp[(size_t)(p + 8 + j) * ROWF];
    }
    int cj[8];
    #pragma unroll
    for (int j = 0; j < 8; ++j) cj[j] = cidl[p + j];
    #pragma unroll
    for (int j = 0; j < 8; ++j) acc[cj[j] * HID + f] += v[j];
    #pragma unroll
    for (int j = 0; j < 8; ++j) v[j] = nv[j];
  }
  __syncthreads();

  float* od = psum + (size_t)b * NCASE * HID;
  for (int c = 0; c < NCASE; ++c)
    od[c * HID + f] = acc[c * HID + f];
  if (t < NCASE) pcnt[b * NCASE + t] = (float)cnth[t];
}

// ---------------------------------------------------------------------------
// K_h0: h0[c][f] = (sum_b psum[b][c][f]) / max(cnt[c],1).
// ---------------------------------------------------------------------------
__global__ __launch_bounds__(128)
void k_h0(const float* __restrict__ psum, const float* __restrict__ pcnt,
          float* __restrict__ h0) {
  __shared__ float cs[128];
  const int c  = blockIdx.x;
  const int fq = blockIdx.y;
  const int t  = threadIdx.x;
  const int f  = fq * 128 + t;

  const float* p = psum + (size_t)c * HID + f;
  float s = 0.f;
  #pragma unroll 8
  for (int b = 0; b < NB; ++b) s += p[(size_t)b * NCASE * HID];

  cs[t] = pcnt[t * NCASE + c] + pcnt[(t + 128) * NCASE + c];
  __syncthreads();
  for (int w = 64; w > 0; w >>= 1) {
    if (t < w) cs[t] += cs[t + w];
    __syncthreads();
  }
  float cnt = fmaxf(cs[0], 1.f);
  h0[(size_t)c * HID + f] = s / cnt;
}

// ---------------------------------------------------------------------------
// K_scale2: scale[row] = g[row] / ||V[row]|| for both layers in one launch.
// ---------------------------------------------------------------------------
__global__ __launch_bounds__(256)
void k_scale2(const float* __restrict__ V0, const float* __restrict__ g0,
              const float* __restrict__ V1, const float* __restrict__ g1,
              float* __restrict__ scale0, float* __restrict__ scale1) {
  __shared__ float red[256];
  const int row = blockIdx.x;               // 0..1023
  const int t   = threadIdx.x;
  const bool first = row < 512;
  const int r = first ? row : row - 512;
  const float* vr = (first ? V0 : V1) + (size_t)r * HID;
  float s = 0.f;
  for (int k = t; k < HID; k += 256) { float v = vr[k]; s += v * v; }
  red[t] = s;
  __syncthreads();
  for (int w = 128; w > 0; w >>= 1) {
    if (t < w) red[t] += red[t + w];
    __syncthreads();
  }
  if (t == 0) {
    float g = first ? g0[r] : g1[r];
    (first ? scale0 : scale1)[r] = g / sqrtf(red[0]);
  }
}

// ---------------------------------------------------------------------------
// K_layer: hout[n][o] = act( scale[o]*dot(hin[n], W[o]) + bias[o] ).
// ---------------------------------------------------------------------------
template <bool SILU, bool SCALED>
__global__ __launch_bounds__(256)
void k_layer(const float* __restrict__ hin, const float* __restrict__ W,
             const float* __restrict__ scale, const float* __restrict__ bias,
             float* __restrict__ hout) {
  __shared__ float hrow[HID];
  const int n = blockIdx.y;
  const int t = threadIdx.x;
  const int o = blockIdx.x * 256 + t;
  for (int f = t; f < HID; f += 256) hrow[f] = hin[(size_t)n * HID + f];
  __syncthreads();
  const float* wr = W + (size_t)o * HID;
  float s0 = 0.f, s1 = 0.f, s2 = 0.f, s3 = 0.f;
  for (int k = 0; k < HID; k += 4) {
    float4 h4 = *(const float4*)&hrow[k];
    float4 w4 = *(const float4*)&wr[k];
    s0 += h4.x * w4.x; s1 += h4.y * w4.y;
    s2 += h4.z * w4.z; s3 += h4.w * w4.w;
  }
  float sdot = (s0 + s1) + (s2 + s3);
  float y = SCALED ? (sdot * scale[o] + bias[o]) : (sdot + bias[o]);
  if (SILU) y = y / (1.f + expf(-y));
  hout[(size_t)n * HID + o] = y;
}

// ---------------------------------------------------------------------------
// K_scatter v2: h3 staged in LDS (128 KB) -> inner loop has NO L2 dependency:
// ds_read (12 cy throughput) + pure sequential plain stores.
// Block owns 256 contiguous points (512 KB sequential store range); 512 thr =
// 128-thread groups each writing full 2 KB rows (half-row/wave contiguous).
// ---------------------------------------------------------------------------
__global__ __launch_bounds__(512)
void k_scatter(const int* __restrict__ cids, const float* __restrict__ h3,
               float* __restrict__ out) {
  __shared__ float hl[NCASE * HID];    // 128 KB
  __shared__ int   cl[256];
  const int t = threadIdx.x;
  const int base = blockIdx.x * 256;

  for (int i = t; i < NCASE * HID / 4; i += 512)
    ((v4f*)hl)[i] = ((const v4f*)h3)[i];
  if (t < 256) cl[t] = cids[base + t];
  __syncthreads();

  const int q = t & 127;               // float4 index within row
  const int g = t >> 7;                // row-group 0..3
  #pragma unroll 8
  for (int p = g; p < 256; p += 4) {
    int c = cl[p];
    v4f hv = *((const v4f*)(hl + c * HID) + q);
    ((v4f*)(out + (size_t)(base + p) * HID))[q] = hv;
  }
}

// ---------------------------------------------------------------------------
extern "C" void kernel_launch(void* const* d_in, const int* in_sizes, int n_in,
                              void* d_out, int out_size, void* d_ws, size_t ws_size,
                              hipStream_t stream) {
  const float* x  = (const float*)d_in[0];
  const float* V0 = (const float*)d_in[1];
  const float* g0 = (const float*)d_in[2];
  const float* b0 = (const float*)d_in[3];
  const float* V1 = (const float*)d_in[4];
  const float* g1 = (const float*)d_in[5];
  const float* b1 = (const float*)d_in[6];
  const float* Wf = (const float*)d_in[7];
  const float* bf = (const float*)d_in[8];
  float* out = (float*)d_out;
  float* ws  = (float*)d_ws;

  size_t off = 0;
  float* psum   = ws + off; off += (size_t)NB * NCASE * HID;    // 32 MB
  float* pcnt   = ws + off; off += NB * NCASE;
  float* h0     = ws + off; off += NCASE * HID;
  float* h1     = ws + off; off += NCASE * HID;
  float* h2     = ws + off; off += NCASE * HID;
  float* h3     = ws + off; off += NCASE * HID;
  float* scale0 = ws + off; off += 512;
  float* scale1 = ws + off; off += 512;
  int*   cids   = (int*)(ws + off); off += NPTS;

  k_scale2<<<dim3(1024), dim3(256), 0, stream>>>(V0, g0, V1, g1, scale0, scale1);
  k_stream<<<dim3(NB), dim3(512), 0, stream>>>(x, psum, pcnt, cids);
  k_h0    <<<dim3(NCASE, 4), dim3(128), 0, stream>>>(psum, pcnt, h0);
  k_layer<true,  true ><<<dim3(2, NCASE), dim3(256), 0, stream>>>(h0, V0, scale0, b0, h1);
  k_layer<true,  true ><<<dim3(2, NCASE), dim3(256), 0, stream>>>(h1, V1, scale1, b1, h2);
  k_layer<false, false><<<dim3(2, NCASE), dim3(256), 0, stream>>>(h2, Wf, nullptr, bf, h3);
  k_scatter<<<dim3(NPTS / 256), dim3(512), 0, stream>>>(cids, h3, out);
}